// Round 1
// baseline (130.890 us; speedup 1.0000x reference)
//
#include <hip/hip_runtime.h>

#define NB 128      // batch
#define NA 100      // atoms (N)
#define KF 32       // INNER
#define NF 33       // F = INNER+1
#define NU 512      // UNITS
#define ND 3        // DEPTH

// ---------------------------------------------------------------------------
// Phase 1: per (b,i) row: S0[b,i,f] = sum_j x[b,i,j,f] (f<32);
//          attr0[b,i,f] = x[b,i,i,f]; bonds[b,i,j] = x[b,i,j,32]
// ---------------------------------------------------------------------------
__global__ __launch_bounds__(256) void p1_reduce(const float* __restrict__ x,
    float* __restrict__ S0, float* __restrict__ attr0, float* __restrict__ bonds)
{
    const int blk = blockIdx.x;            // b*NA + i
    const int i   = blk % NA;
    const int t   = threadIdx.x;

    __shared__ float lds[NA * NF];         // 3300 floats = 13.2 KB
    __shared__ float red[8][KF];

    const float4* row4 = (const float4*)(x + (size_t)blk * (NA * NF));
    float4* lds4 = (float4*)lds;
    for (int idx = t; idx < (NA * NF) / 4; idx += 256) lds4[idx] = row4[idx];
    __syncthreads();

    const int g = t >> 5;                  // 0..7
    const int f = t & 31;
    float partial = 0.f;
    for (int j = g; j < NA; j += 8) partial += lds[j * NF + f];   // bank = (j+f)%32: conflict-free
    red[g][f] = partial;
    __syncthreads();

    if (t < KF) {
        float s = 0.f;
#pragma unroll
        for (int gg = 0; gg < 8; ++gg) s += red[gg][t];
        S0[(size_t)blk * KF + t] = s;
    } else if (t >= 64 && t < 64 + KF) {
        attr0[(size_t)blk * KF + (t - 64)] = lds[i * NF + (t - 64)];
    } else if (t >= 128 && t < 128 + NA) {
        const int j = t - 128;
        bonds[(size_t)blk * NA + j] = lds[j * NF + KF];
    }
}

// ---------------------------------------------------------------------------
// Phase 2: per batch b. State per row i: attr[i][32], S[i][32], rs[i].
//   d=0: fp += sum_i softmax(attr_i @ Wout[0] + bout[0])
//   d>0: core = S@Winner[d]+binner[d]; delta=core-attr; attr=core; S+=rs*delta
//        fp += sum_i softmax(attr_i @ Wout[d] + bout[d])
// ---------------------------------------------------------------------------
__global__ __launch_bounds__(512) void p2_compute(
    const float* __restrict__ S0, const float* __restrict__ attr0,
    const float* __restrict__ bonds,
    const float* __restrict__ W_inner, const float* __restrict__ b_inner,
    const float* __restrict__ W_output, const float* __restrict__ b_output,
    float* __restrict__ out)
{
    extern __shared__ float sm[];
    float* attrS = sm;               // [128*32] (rows 100..127 zero pad)
    float* Ssh   = sm + 4096;        // [128*32]
    float* Wl    = sm + 8192;        // [32*512] = 64 KB
    float* rs    = sm + 24576;       // [128]
    float* fp8   = Wl;               // overlay: [8*512] used after depth loop

    const int b    = blockIdx.x;
    const int t    = threadIdx.x;
    const int lane = t & 63;
    const int w    = t >> 6;         // wave 0..7

    // load attr0 / S0 (800 float4s)
    const float4* a4 = (const float4*)(attr0 + (size_t)b * NA * KF);
    const float4* s4 = (const float4*)(S0    + (size_t)b * NA * KF);
#pragma unroll
    for (int it = 0; it < 2; ++it) {
        int idx = t + it * 512;
        if (idx < NA * KF / 4) { ((float4*)attrS)[idx] = a4[idx]; ((float4*)Ssh)[idx] = s4[idx]; }
    }
    for (int idx = NA * KF + t; idx < 128 * KF; idx += 512) { attrS[idx] = 0.f; Ssh[idx] = 0.f; }

    // rs[i] = 1 + sum_j bonds[b][j][i]   (coalesced across t per j)
    if (t < NA) {
        float c = 0.f;
        const float* bb = bonds + (size_t)b * NA * NA + t;
        for (int j = 0; j < NA; ++j) c += bb[j * NA];
        rs[t] = 1.f + c;
    }

    float fpacc[8];
#pragma unroll
    for (int c = 0; c < 8; ++c) fpacc[c] = 0.f;

    __syncthreads();

    for (int d = 0; d <= ND; ++d) {
        if (d > 0) {
            // core = Ssh[:, :32] @ W_inner[d] + b_inner[d]
            float corev[7];
#pragma unroll
            for (int it = 0; it < 7; ++it) {
                int idx = t + it * 512;
                if (idx < NA * KF) {
                    int row = idx >> 5, f = idx & 31;
                    float acc = b_inner[d * KF + f];
                    const float* Wi = W_inner + d * KF * KF + f;
                    const float* Sr = Ssh + row * KF;
#pragma unroll
                    for (int k = 0; k < KF; ++k) acc += Sr[k] * Wi[k * KF];
                    corev[it] = acc;
                }
            }
            __syncthreads();   // everyone done reading Ssh/attrS (incl. prev logits)
#pragma unroll
            for (int it = 0; it < 7; ++it) {
                int idx = t + it * 512;
                if (idx < NA * KF) {
                    int row = idx >> 5;
                    float cc = corev[it];
                    float delta = cc - attrS[idx];
                    attrS[idx] = cc;
                    Ssh[idx] += rs[row] * delta;
                }
            }
        }
        // stage W_output[d] into LDS (4096 float4s)
        {
            const float4* wo4 = (const float4*)(W_output + (size_t)d * KF * NU);
            float4* wl4 = (float4*)Wl;
            for (int idx = t; idx < KF * NU / 4; idx += 512) wl4[idx] = wo4[idx];
        }
        __syncthreads();

        // bias (b_output[d]) straight from global (L2-hot)
        const float4 bv0 = *(const float4*)&b_output[d * NU + lane * 8];
        const float4 bv1 = *(const float4*)&b_output[d * NU + lane * 8 + 4];

        // logits + softmax + accumulate: 8 waves x 4 rows/pass, 8 units/lane
        for (int p = 0; p < 4; ++p) {
            const int r0 = p * 32 + w * 4;
            if (r0 >= NA) continue;                       // wave-uniform
            float acc[4][8];
#pragma unroll
            for (int r = 0; r < 4; ++r) {
                acc[r][0] = bv0.x; acc[r][1] = bv0.y; acc[r][2] = bv0.z; acc[r][3] = bv0.w;
                acc[r][4] = bv1.x; acc[r][5] = bv1.y; acc[r][6] = bv1.z; acc[r][7] = bv1.w;
            }
            for (int k4 = 0; k4 < KF; k4 += 4) {
                float4 av[4];
#pragma unroll
                for (int r = 0; r < 4; ++r) av[r] = *(const float4*)&attrS[(r0 + r) * KF + k4];
#pragma unroll
                for (int kk = 0; kk < 4; ++kk) {
                    const float4 w0 = *(const float4*)&Wl[(k4 + kk) * NU + lane * 8];
                    const float4 w1 = *(const float4*)&Wl[(k4 + kk) * NU + lane * 8 + 4];
#pragma unroll
                    for (int r = 0; r < 4; ++r) {
                        const float a = (&av[r].x)[kk];
                        acc[r][0] += a * w0.x; acc[r][1] += a * w0.y;
                        acc[r][2] += a * w0.z; acc[r][3] += a * w0.w;
                        acc[r][4] += a * w1.x; acc[r][5] += a * w1.y;
                        acc[r][6] += a * w1.z; acc[r][7] += a * w1.w;
                    }
                }
            }
#pragma unroll
            for (int r = 0; r < 4; ++r) {
                const int row = r0 + r;
                if (row >= NA) continue;
                float m = acc[r][0];
#pragma unroll
                for (int c = 1; c < 8; ++c) m = fmaxf(m, acc[r][c]);
#pragma unroll
                for (int off = 32; off > 0; off >>= 1) m = fmaxf(m, __shfl_xor(m, off, 64));
                float e[8], s = 0.f;
#pragma unroll
                for (int c = 0; c < 8; ++c) { e[c] = __expf(acc[r][c] - m); s += e[c]; }
#pragma unroll
                for (int off = 32; off > 0; off >>= 1) s += __shfl_xor(s, off, 64);
                const float inv = 1.f / s;
#pragma unroll
                for (int c = 0; c < 8; ++c) fpacc[c] += e[c] * inv;
            }
        }
    }

    // deterministic cross-wave reduce of fp (overlay on Wl region)
    __syncthreads();
    {
        float4 f0 = {fpacc[0], fpacc[1], fpacc[2], fpacc[3]};
        float4 f1 = {fpacc[4], fpacc[5], fpacc[6], fpacc[7]};
        *(float4*)&fp8[w * NU + lane * 8]     = f0;
        *(float4*)&fp8[w * NU + lane * 8 + 4] = f1;
    }
    __syncthreads();
    float s = fp8[t];
#pragma unroll
    for (int ww = 1; ww < 8; ++ww) s += fp8[ww * NU + t];
    out[(size_t)b * NU + t] = s;
}

// ---------------------------------------------------------------------------
extern "C" void kernel_launch(void* const* d_in, const int* in_sizes, int n_in,
                              void* d_out, int out_size, void* d_ws, size_t ws_size,
                              hipStream_t stream) {
    (void)in_sizes; (void)n_in; (void)out_size; (void)ws_size;
    const float* x        = (const float*)d_in[0];
    const float* W_inner  = (const float*)d_in[1];
    const float* b_inner  = (const float*)d_in[2];
    const float* W_output = (const float*)d_in[3];
    const float* b_output = (const float*)d_in[4];
    float* out = (float*)d_out;

    float* S0    = (float*)d_ws;             // 128*100*32
    float* attr0 = S0 + (size_t)NB * NA * KF;
    float* bonds = attr0 + (size_t)NB * NA * KF;  // 128*100*100

    p1_reduce<<<NB * NA, 256, 0, stream>>>(x, S0, attr0, bonds);

    const size_t smem = (4096 + 4096 + 16384 + 128) * sizeof(float);  // ~96.5 KB
    hipFuncSetAttribute(reinterpret_cast<const void*>(p2_compute),
                        hipFuncAttributeMaxDynamicSharedMemorySize, (int)smem);
    p2_compute<<<NB, 512, smem, stream>>>(S0, attr0, bonds, W_inner, b_inner,
                                          W_output, b_output, out);
}

// Round 2
// 87.709 us; speedup vs baseline: 1.4923x; 1.4923x over previous
//
#include <hip/hip_runtime.h>

#define NB 128      // batch
#define NA 100      // atoms (N)
#define KF 32       // INNER
#define NF 33       // F = INNER+1
#define NU 512      // UNITS
#define ND 3        // DEPTH

// ws layout (floats):
//   S0      : NB*NA*KF            = 409600
//   bonds   : NB*NA*NA            = 1280000   (fpPart overlays this after p2a)
//   attrAll : NB*(ND+1)*NA*KF     = 1638400
#define SZ_S0    (NB * NA * KF)
#define SZ_BONDS (NB * NA * NA)

// ---------------------------------------------------------------------------
// Phase 1: per (b,i) row: S0[b,i,f] = sum_j x[b,i,j,f] (f<32);
//          attrAll[b,0,i,f] = x[b,i,i,f]; bonds[b,i,j] = x[b,i,j,32]
// ---------------------------------------------------------------------------
__global__ __launch_bounds__(256) void p1_reduce(const float* __restrict__ x,
    float* __restrict__ S0, float* __restrict__ attrAll, float* __restrict__ bonds)
{
    const int blk = blockIdx.x;            // b*NA + i
    const int b   = blk / NA;
    const int i   = blk % NA;
    const int t   = threadIdx.x;

    __shared__ float lds[NA * NF];         // 13.2 KB
    __shared__ float red[8][KF];

    const float4* row4 = (const float4*)(x + (size_t)blk * (NA * NF));
    float4* lds4 = (float4*)lds;
    for (int idx = t; idx < (NA * NF) / 4; idx += 256) lds4[idx] = row4[idx];
    __syncthreads();

    const int g = t >> 5;                  // 0..7
    const int f = t & 31;
    float partial = 0.f;
    for (int j = g; j < NA; j += 8) partial += lds[j * NF + f];   // conflict-free
    red[g][f] = partial;
    __syncthreads();

    if (t < KF) {
        float s = 0.f;
#pragma unroll
        for (int gg = 0; gg < 8; ++gg) s += red[gg][t];
        S0[(size_t)blk * KF + t] = s;
    } else if (t >= 64 && t < 64 + KF) {
        // attrAll[b][0][i][f]
        attrAll[(size_t)b * (ND + 1) * NA * KF + (size_t)i * KF + (t - 64)] = lds[i * NF + (t - 64)];
    } else if (t >= 128 && t < 128 + NA) {
        const int j = t - 128;
        bonds[(size_t)blk * NA + j] = lds[j * NF + KF];
    }
}

// ---------------------------------------------------------------------------
// Phase 2a: per-batch recurrence. Produces attrAll[b][d] for d=1..ND.
//   rs[i] = 1 + sum_j bonds[j][i]
//   d>0: core = S @ W_inner[d] + b_inner[d]; delta = core - attr;
//        attr = core; S += rs[:,None]*delta
// ---------------------------------------------------------------------------
__global__ __launch_bounds__(256) void p2a_recur(
    const float* __restrict__ S0, const float* __restrict__ bonds,
    const float* __restrict__ W_inner, const float* __restrict__ b_inner,
    float* __restrict__ attrAll)
{
    __shared__ float S[NA * KF];      // 3200
    __shared__ float attr[NA * KF];   // 3200
    __shared__ float Wi[KF * KF];     // 1024
    __shared__ float rs[NA];

    const int b = blockIdx.x;
    const int t = threadIdx.x;

    const float4* s4 = (const float4*)(S0 + (size_t)b * NA * KF);
    const float4* a4 = (const float4*)(attrAll + (size_t)b * (ND + 1) * NA * KF);
    for (int idx = t; idx < NA * KF / 4; idx += 256) {
        ((float4*)S)[idx]    = s4[idx];
        ((float4*)attr)[idx] = a4[idx];
    }
    if (t < NA) {
        float c = 0.f;
        const float* bb = bonds + (size_t)b * NA * NA + t;
        for (int j = 0; j < NA; ++j) c += bb[j * NA];
        rs[t] = 1.f + c;
    }
    __syncthreads();

    for (int d = 1; d <= ND; ++d) {
        if (t < KF * KF / 4)
            ((float4*)Wi)[t] = ((const float4*)(W_inner + d * KF * KF))[t];
        __syncthreads();

        float core[13];
#pragma unroll
        for (int it = 0; it < 13; ++it) {
            const int idx = t + it * 256;
            if (idx < NA * KF) {
                const int row = idx >> 5, f = idx & 31;
                float acc = b_inner[d * KF + f];
                const float* Sr = S + row * KF;
#pragma unroll
                for (int k = 0; k < KF; ++k) acc += Sr[k] * Wi[k * KF + f];
                core[it] = acc;
            }
        }
        __syncthreads();
#pragma unroll
        for (int it = 0; it < 13; ++it) {
            const int idx = t + it * 256;
            if (idx < NA * KF) {
                const int row = idx >> 5;
                const float cc  = core[it];
                const float old = attr[idx];
                attr[idx] = cc;
                S[idx] += rs[row] * (cc - old);
                attrAll[(size_t)b * (ND + 1) * NA * KF + (size_t)d * NA * KF + idx] = cc;
            }
        }
        __syncthreads();
    }
}

// ---------------------------------------------------------------------------
// Phase 2b: one block per (b,d): fpPart[d][b][u] = sum_i softmax(attr_i@Wout[d]+bout[d])[u]
// 512 threads = 8 waves; each wave does 4 rows/pass; 100 rows = 25 wave-passes.
// Lane's 8 units: lane*4+{0..3} and 256+lane*4+{0..3}  (stride-16B LDS reads,
// conflict-free ds_read_b128).
// ---------------------------------------------------------------------------
__global__ __launch_bounds__(512) void p2b_fp(
    const float* __restrict__ attrAll, const float* __restrict__ W_output,
    const float* __restrict__ b_output, float* __restrict__ fpPart)
{
    extern __shared__ float sm[];
    float* Wl    = sm;            // [32*512] = 64 KB
    float* attrL = sm + KF * NU;  // [100*32] = 12.8 KB

    const int blk  = blockIdx.x;
    const int b    = blk & (NB - 1);
    const int d    = blk >> 7;
    const int t    = threadIdx.x;
    const int lane = t & 63;
    const int w    = t >> 6;

    const float4* wo4 = (const float4*)(W_output + (size_t)d * KF * NU);
    for (int idx = t; idx < KF * NU / 4; idx += 512) ((float4*)Wl)[idx] = wo4[idx];
    const float4* a4 = (const float4*)(attrAll + ((size_t)b * (ND + 1) + d) * NA * KF);
    for (int idx = t; idx < NA * KF / 4; idx += 512) ((float4*)attrL)[idx] = a4[idx];

    const float4 bv0 = *(const float4*)&b_output[d * NU + lane * 4];
    const float4 bv1 = *(const float4*)&b_output[d * NU + 256 + lane * 4];

    float fpacc[8];
#pragma unroll
    for (int c = 0; c < 8; ++c) fpacc[c] = 0.f;

    __syncthreads();

    for (int p = 0; p < 4; ++p) {
        const int r0 = p * 32 + w * 4;
        if (r0 >= NA) continue;                      // wave-uniform
        float acc[4][8];
#pragma unroll
        for (int r = 0; r < 4; ++r) {
            acc[r][0] = bv0.x; acc[r][1] = bv0.y; acc[r][2] = bv0.z; acc[r][3] = bv0.w;
            acc[r][4] = bv1.x; acc[r][5] = bv1.y; acc[r][6] = bv1.z; acc[r][7] = bv1.w;
        }
        for (int k4 = 0; k4 < KF; k4 += 4) {
            float4 av[4];
#pragma unroll
            for (int r = 0; r < 4; ++r) av[r] = *(const float4*)&attrL[(r0 + r) * KF + k4];
#pragma unroll
            for (int kk = 0; kk < 4; ++kk) {
                const float4 w0 = *(const float4*)&Wl[(k4 + kk) * NU + lane * 4];
                const float4 w1 = *(const float4*)&Wl[(k4 + kk) * NU + 256 + lane * 4];
#pragma unroll
                for (int r = 0; r < 4; ++r) {
                    const float a = (&av[r].x)[kk];
                    acc[r][0] += a * w0.x; acc[r][1] += a * w0.y;
                    acc[r][2] += a * w0.z; acc[r][3] += a * w0.w;
                    acc[r][4] += a * w1.x; acc[r][5] += a * w1.y;
                    acc[r][6] += a * w1.z; acc[r][7] += a * w1.w;
                }
            }
        }
#pragma unroll
        for (int r = 0; r < 4; ++r) {
            float m = acc[r][0];
#pragma unroll
            for (int c = 1; c < 8; ++c) m = fmaxf(m, acc[r][c]);
#pragma unroll
            for (int off = 32; off > 0; off >>= 1) m = fmaxf(m, __shfl_xor(m, off, 64));
            float e[8], s = 0.f;
#pragma unroll
            for (int c = 0; c < 8; ++c) { e[c] = __expf(acc[r][c] - m); s += e[c]; }
#pragma unroll
            for (int off = 32; off > 0; off >>= 1) s += __shfl_xor(s, off, 64);
            const float inv = 1.f / s;
#pragma unroll
            for (int c = 0; c < 8; ++c) fpacc[c] += e[c] * inv;
        }
    }

    // cross-wave reduce (overlay on Wl)
    __syncthreads();
    float* fp8 = Wl;
    {
        float4 f0 = {fpacc[0], fpacc[1], fpacc[2], fpacc[3]};
        float4 f1 = {fpacc[4], fpacc[5], fpacc[6], fpacc[7]};
        *(float4*)&fp8[w * NU + lane * 4]       = f0;
        *(float4*)&fp8[w * NU + 256 + lane * 4] = f1;
    }
    __syncthreads();
    float s = fp8[t];
#pragma unroll
    for (int ww = 1; ww < 8; ++ww) s += fp8[ww * NU + t];
    fpPart[((size_t)d * NB + b) * NU + t] = s;
}

// ---------------------------------------------------------------------------
// Phase 2c: out[b][u] = sum_d fpPart[d][b][u]
// ---------------------------------------------------------------------------
__global__ __launch_bounds__(512) void p2c_out(const float* __restrict__ fpPart,
                                               float* __restrict__ out)
{
    const int b = blockIdx.x, t = threadIdx.x;
    float s = 0.f;
#pragma unroll
    for (int d = 0; d <= ND; ++d) s += fpPart[((size_t)d * NB + b) * NU + t];
    out[(size_t)b * NU + t] = s;
}

// ---------------------------------------------------------------------------
extern "C" void kernel_launch(void* const* d_in, const int* in_sizes, int n_in,
                              void* d_out, int out_size, void* d_ws, size_t ws_size,
                              hipStream_t stream) {
    (void)in_sizes; (void)n_in; (void)out_size; (void)ws_size;
    const float* x        = (const float*)d_in[0];
    const float* W_inner  = (const float*)d_in[1];
    const float* b_inner  = (const float*)d_in[2];
    const float* W_output = (const float*)d_in[3];
    const float* b_output = (const float*)d_in[4];
    float* out = (float*)d_out;

    float* S0      = (float*)d_ws;
    float* bonds   = S0 + SZ_S0;
    float* attrAll = bonds + SZ_BONDS;
    float* fpPart  = bonds;               // overlay: bonds dead after p2a

    p1_reduce<<<NB * NA, 256, 0, stream>>>(x, S0, attrAll, bonds);
    p2a_recur<<<NB, 256, 0, stream>>>(S0, bonds, W_inner, b_inner, attrAll);

    const size_t smemB = (size_t)(KF * NU + NA * KF) * sizeof(float);  // 78.3 KB
    hipFuncSetAttribute(reinterpret_cast<const void*>(p2b_fp),
                        hipFuncAttributeMaxDynamicSharedMemorySize, (int)smemB);
    p2b_fp<<<NB * (ND + 1), 512, smemB, stream>>>(attrAll, W_output, b_output, fpPart);
    p2c_out<<<NB, 512, 0, stream>>>(fpPart, out);
}

// Round 3
// 86.590 us; speedup vs baseline: 1.5116x; 1.0129x over previous
//
#include <hip/hip_runtime.h>

#define NB 128      // batch
#define NA 100      // atoms (N)
#define KF 32       // INNER
#define NF 33       // F = INNER+1
#define NU 512      // UNITS
#define ND 3        // DEPTH

// ws layout (floats):
//   S0      : NB*NA*KF            = 409600
//   bonds   : NB*NA*NA            = 1280000   (fpPart overlays this after p2a)
//   attrAll : NB*(ND+1)*NA*KF     = 1638400
#define SZ_S0    (NB * NA * KF)
#define SZ_BONDS (NB * NA * NA)

// ---------------------------------------------------------------------------
// Phase 1: per (b,i) row: S0[b,i,f] = sum_j x[b,i,j,f] (f<32);
//          attrAll[b,0,i,f] = x[b,i,i,f]; bonds[b,i,j] = x[b,i,j,32]
// ---------------------------------------------------------------------------
__global__ __launch_bounds__(256) void p1_reduce(const float* __restrict__ x,
    float* __restrict__ S0, float* __restrict__ attrAll, float* __restrict__ bonds)
{
    const int blk = blockIdx.x;            // b*NA + i
    const int b   = blk / NA;
    const int i   = blk % NA;
    const int t   = threadIdx.x;

    __shared__ float lds[NA * NF];         // 13.2 KB
    __shared__ float red[8][KF];

    const float4* row4 = (const float4*)(x + (size_t)blk * (NA * NF));
    float4* lds4 = (float4*)lds;
    for (int idx = t; idx < (NA * NF) / 4; idx += 256) lds4[idx] = row4[idx];
    __syncthreads();

    const int g = t >> 5;                  // 0..7
    const int f = t & 31;
    // two independent accumulator chains (j and j+8, stride 16)
    float p0 = 0.f, p1 = 0.f;
    for (int j = g; j + 8 < NA; j += 16) {
        p0 += lds[j * NF + f];
        p1 += lds[(j + 8) * NF + f];
    }
    if (g < 4) p0 += lds[(96 + g) * NF + f];   // tail rows 96..99
    red[g][f] = p0 + p1;
    __syncthreads();

    if (t < KF) {
        float s = 0.f;
#pragma unroll
        for (int gg = 0; gg < 8; ++gg) s += red[gg][t];
        S0[(size_t)blk * KF + t] = s;
    } else if (t >= 64 && t < 64 + KF) {
        // attrAll[b][0][i][f]
        attrAll[(size_t)b * (ND + 1) * NA * KF + (size_t)i * KF + (t - 64)] = lds[i * NF + (t - 64)];
    } else if (t >= 128 && t < 128 + NA) {
        const int j = t - 128;
        bonds[(size_t)blk * NA + j] = lds[j * NF + KF];
    }
}

// ---------------------------------------------------------------------------
// Phase 2a: per-batch recurrence. Produces attrAll[b][d] for d=1..ND.
//   rs[i] = 1 + sum_j bonds[j][i]
//   d>0: core = S @ W_inner[d] + b_inner[d]; delta = core - attr;
//        attr = core; S += rs[:,None]*delta
// ---------------------------------------------------------------------------
__global__ __launch_bounds__(256) void p2a_recur(
    const float* __restrict__ S0, const float* __restrict__ bonds,
    const float* __restrict__ W_inner, const float* __restrict__ b_inner,
    float* __restrict__ attrAll)
{
    __shared__ float S[NA * KF];      // 3200
    __shared__ float attr[NA * KF];   // 3200
    __shared__ float Wi[KF * KF];     // 1024
    __shared__ float rs[NA];

    const int b = blockIdx.x;
    const int t = threadIdx.x;

    const float4* s4 = (const float4*)(S0 + (size_t)b * NA * KF);
    const float4* a4 = (const float4*)(attrAll + (size_t)b * (ND + 1) * NA * KF);
    for (int idx = t; idx < NA * KF / 4; idx += 256) {
        ((float4*)S)[idx]    = s4[idx];
        ((float4*)attr)[idx] = a4[idx];
    }
    if (t < NA) {
        // 8 independent accumulator chains: loads pipeline instead of
        // serializing on a single dependent fp-add chain.
        const float* bb = bonds + (size_t)b * NA * NA + t;
        float c0=0.f,c1=0.f,c2=0.f,c3=0.f,c4=0.f,c5=0.f,c6=0.f,c7=0.f;
        int j = 0;
        for (; j + 8 <= NA; j += 8) {
            c0 += bb[(j+0)*NA]; c1 += bb[(j+1)*NA];
            c2 += bb[(j+2)*NA]; c3 += bb[(j+3)*NA];
            c4 += bb[(j+4)*NA]; c5 += bb[(j+5)*NA];
            c6 += bb[(j+6)*NA]; c7 += bb[(j+7)*NA];
        }
        for (; j < NA; ++j) c0 += bb[j*NA];
        rs[t] = 1.f + (((c0+c1)+(c2+c3))+((c4+c5)+(c6+c7)));
    }
    __syncthreads();

    for (int d = 1; d <= ND; ++d) {
        if (t < KF * KF / 4)
            ((float4*)Wi)[t] = ((const float4*)(W_inner + d * KF * KF))[t];
        __syncthreads();

        float core[13];
#pragma unroll
        for (int it = 0; it < 13; ++it) {
            const int idx = t + it * 256;
            if (idx < NA * KF) {
                const int row = idx >> 5, f = idx & 31;
                float acc = b_inner[d * KF + f];
                const float* Sr = S + row * KF;
#pragma unroll
                for (int k = 0; k < KF; ++k) acc += Sr[k] * Wi[k * KF + f];
                core[it] = acc;
            }
        }
        __syncthreads();
#pragma unroll
        for (int it = 0; it < 13; ++it) {
            const int idx = t + it * 256;
            if (idx < NA * KF) {
                const int row = idx >> 5;
                const float cc  = core[it];
                const float old = attr[idx];
                attr[idx] = cc;
                S[idx] += rs[row] * (cc - old);
                attrAll[(size_t)b * (ND + 1) * NA * KF + (size_t)d * NA * KF + idx] = cc;
            }
        }
        __syncthreads();
    }
}

// ---------------------------------------------------------------------------
// Phase 2b: one block per (b,d): fpPart[d][b][u] = sum_i softmax(attr_i@Wout[d]+bout[d])[u]
// 512 threads = 8 waves; each wave does 4 rows/pass; 100 rows = 25 wave-passes.
// ---------------------------------------------------------------------------
__global__ __launch_bounds__(512) void p2b_fp(
    const float* __restrict__ attrAll, const float* __restrict__ W_output,
    const float* __restrict__ b_output, float* __restrict__ fpPart)
{
    extern __shared__ float sm[];
    float* Wl    = sm;            // [32*512] = 64 KB
    float* attrL = sm + KF * NU;  // [100*32] = 12.8 KB

    const int blk  = blockIdx.x;
    const int b    = blk & (NB - 1);
    const int d    = blk >> 7;
    const int t    = threadIdx.x;
    const int lane = t & 63;
    const int w    = t >> 6;

    const float4* wo4 = (const float4*)(W_output + (size_t)d * KF * NU);
    for (int idx = t; idx < KF * NU / 4; idx += 512) ((float4*)Wl)[idx] = wo4[idx];
    const float4* a4 = (const float4*)(attrAll + ((size_t)b * (ND + 1) + d) * NA * KF);
    for (int idx = t; idx < NA * KF / 4; idx += 512) ((float4*)attrL)[idx] = a4[idx];

    const float4 bv0 = *(const float4*)&b_output[d * NU + lane * 4];
    const float4 bv1 = *(const float4*)&b_output[d * NU + 256 + lane * 4];

    float fpacc[8];
#pragma unroll
    for (int c = 0; c < 8; ++c) fpacc[c] = 0.f;

    __syncthreads();

    for (int p = 0; p < 4; ++p) {
        const int r0 = p * 32 + w * 4;
        if (r0 >= NA) continue;                      // wave-uniform
        float acc[4][8];
#pragma unroll
        for (int r = 0; r < 4; ++r) {
            acc[r][0] = bv0.x; acc[r][1] = bv0.y; acc[r][2] = bv0.z; acc[r][3] = bv0.w;
            acc[r][4] = bv1.x; acc[r][5] = bv1.y; acc[r][6] = bv1.z; acc[r][7] = bv1.w;
        }
        for (int k4 = 0; k4 < KF; k4 += 4) {
            float4 av[4];
#pragma unroll
            for (int r = 0; r < 4; ++r) av[r] = *(const float4*)&attrL[(r0 + r) * KF + k4];
#pragma unroll
            for (int kk = 0; kk < 4; ++kk) {
                const float4 w0 = *(const float4*)&Wl[(k4 + kk) * NU + lane * 4];
                const float4 w1 = *(const float4*)&Wl[(k4 + kk) * NU + 256 + lane * 4];
#pragma unroll
                for (int r = 0; r < 4; ++r) {
                    const float a = (&av[r].x)[kk];
                    acc[r][0] += a * w0.x; acc[r][1] += a * w0.y;
                    acc[r][2] += a * w0.z; acc[r][3] += a * w0.w;
                    acc[r][4] += a * w1.x; acc[r][5] += a * w1.y;
                    acc[r][6] += a * w1.z; acc[r][7] += a * w1.w;
                }
            }
        }
#pragma unroll
        for (int r = 0; r < 4; ++r) {
            float m = acc[r][0];
#pragma unroll
            for (int c = 1; c < 8; ++c) m = fmaxf(m, acc[r][c]);
#pragma unroll
            for (int off = 32; off > 0; off >>= 1) m = fmaxf(m, __shfl_xor(m, off, 64));
            float e[8], s = 0.f;
#pragma unroll
            for (int c = 0; c < 8; ++c) { e[c] = __expf(acc[r][c] - m); s += e[c]; }
#pragma unroll
            for (int off = 32; off > 0; off >>= 1) s += __shfl_xor(s, off, 64);
            const float inv = 1.f / s;
#pragma unroll
            for (int c = 0; c < 8; ++c) fpacc[c] += e[c] * inv;
        }
    }

    // cross-wave reduce (overlay on Wl)
    __syncthreads();
    float* fp8 = Wl;
    {
        float4 f0 = {fpacc[0], fpacc[1], fpacc[2], fpacc[3]};
        float4 f1 = {fpacc[4], fpacc[5], fpacc[6], fpacc[7]};
        *(float4*)&fp8[w * NU + lane * 4]       = f0;
        *(float4*)&fp8[w * NU + 256 + lane * 4] = f1;
    }
    __syncthreads();
    float s = fp8[t];
#pragma unroll
    for (int ww = 1; ww < 8; ++ww) s += fp8[ww * NU + t];
    fpPart[((size_t)d * NB + b) * NU + t] = s;
}

// ---------------------------------------------------------------------------
// Phase 2c: out[b][u] = sum_d fpPart[d][b][u]
// ---------------------------------------------------------------------------
__global__ __launch_bounds__(512) void p2c_out(const float* __restrict__ fpPart,
                                               float* __restrict__ out)
{
    const int b = blockIdx.x, t = threadIdx.x;
    float s = 0.f;
#pragma unroll
    for (int d = 0; d <= ND; ++d) s += fpPart[((size_t)d * NB + b) * NU + t];
    out[(size_t)b * NU + t] = s;
}

// ---------------------------------------------------------------------------
extern "C" void kernel_launch(void* const* d_in, const int* in_sizes, int n_in,
                              void* d_out, int out_size, void* d_ws, size_t ws_size,
                              hipStream_t stream) {
    (void)in_sizes; (void)n_in; (void)out_size; (void)ws_size;
    const float* x        = (const float*)d_in[0];
    const float* W_inner  = (const float*)d_in[1];
    const float* b_inner  = (const float*)d_in[2];
    const float* W_output = (const float*)d_in[3];
    const float* b_output = (const float*)d_in[4];
    float* out = (float*)d_out;

    float* S0      = (float*)d_ws;
    float* bonds   = S0 + SZ_S0;
    float* attrAll = bonds + SZ_BONDS;
    float* fpPart  = bonds;               // overlay: bonds dead after p2a

    p1_reduce<<<NB * NA, 256, 0, stream>>>(x, S0, attrAll, bonds);
    p2a_recur<<<NB, 256, 0, stream>>>(S0, bonds, W_inner, b_inner, attrAll);

    const size_t smemB = (size_t)(KF * NU + NA * KF) * sizeof(float);  // 78.3 KB
    hipFuncSetAttribute(reinterpret_cast<const void*>(p2b_fp),
                        hipFuncAttributeMaxDynamicSharedMemorySize, (int)smemB);
    p2b_fp<<<NB * (ND + 1), 512, smemB, stream>>>(attrAll, W_output, b_output, fpPart);
    p2c_out<<<NB, 512, 0, stream>>>(fpPart, out);
}

// Round 4
// 85.709 us; speedup vs baseline: 1.5272x; 1.0103x over previous
//
#include <hip/hip_runtime.h>

#define NB 128      // batch
#define NA 100      // atoms (N)
#define KF 32       // INNER
#define NF 33       // F = INNER+1
#define NU 512      // UNITS
#define ND 3        // DEPTH

// ws layout (floats):
//   S0      : NB*NA*KF            = 409600
//   bonds   : NB*NA*NA            = 1280000   (fpPart overlays this after p2a)
//   attrAll : NB*(ND+1)*NA*KF     = 1638400
#define SZ_S0    (NB * NA * KF)
#define SZ_BONDS (NB * NA * NA)

// ---------------------------------------------------------------------------
// Phase 1: per (b,i) row: S0[b,i,f] = sum_j x[b,i,j,f] (f<32);
//          attrAll[b,0,i,f] = x[b,i,i,f]; bonds[b,i,j] = x[b,i,j,32]
// ---------------------------------------------------------------------------
__global__ __launch_bounds__(256) void p1_reduce(const float* __restrict__ x,
    float* __restrict__ S0, float* __restrict__ attrAll, float* __restrict__ bonds)
{
    const int blk = blockIdx.x;            // b*NA + i
    const int b   = blk / NA;
    const int i   = blk % NA;
    const int t   = threadIdx.x;

    __shared__ float lds[NA * NF];         // 13.2 KB
    __shared__ float red[8][KF];

    const float4* row4 = (const float4*)(x + (size_t)blk * (NA * NF));
    float4* lds4 = (float4*)lds;
    for (int idx = t; idx < (NA * NF) / 4; idx += 256) lds4[idx] = row4[idx];
    __syncthreads();

    const int g = t >> 5;                  // 0..7
    const int f = t & 31;
    float p0 = 0.f, p1 = 0.f;
    for (int j = g; j + 8 < NA; j += 16) {
        p0 += lds[j * NF + f];
        p1 += lds[(j + 8) * NF + f];
    }
    if (g < 4) p0 += lds[(96 + g) * NF + f];   // tail rows 96..99
    red[g][f] = p0 + p1;
    __syncthreads();

    if (t < KF) {
        float s = 0.f;
#pragma unroll
        for (int gg = 0; gg < 8; ++gg) s += red[gg][t];
        S0[(size_t)blk * KF + t] = s;
    } else if (t >= 64 && t < 64 + KF) {
        attrAll[(size_t)b * (ND + 1) * NA * KF + (size_t)i * KF + (t - 64)] = lds[i * NF + (t - 64)];
    } else if (t >= 128 && t < 128 + NA) {
        const int j = t - 128;
        bonds[(size_t)blk * NA + j] = lds[j * NF + KF];
    }
}

// ---------------------------------------------------------------------------
// Phase 2a: per-batch recurrence. Produces attrAll[b][d] for d=1..ND.
// ---------------------------------------------------------------------------
__global__ __launch_bounds__(256) void p2a_recur(
    const float* __restrict__ S0, const float* __restrict__ bonds,
    const float* __restrict__ W_inner, const float* __restrict__ b_inner,
    float* __restrict__ attrAll)
{
    __shared__ float S[NA * KF];      // 3200
    __shared__ float attr[NA * KF];   // 3200
    __shared__ float Wi[KF * KF];     // 1024
    __shared__ float rs[NA];

    const int b = blockIdx.x;
    const int t = threadIdx.x;

    const float4* s4 = (const float4*)(S0 + (size_t)b * NA * KF);
    const float4* a4 = (const float4*)(attrAll + (size_t)b * (ND + 1) * NA * KF);
    for (int idx = t; idx < NA * KF / 4; idx += 256) {
        ((float4*)S)[idx]    = s4[idx];
        ((float4*)attr)[idx] = a4[idx];
    }
    if (t < NA) {
        const float* bb = bonds + (size_t)b * NA * NA + t;
        float c0=0.f,c1=0.f,c2=0.f,c3=0.f,c4=0.f,c5=0.f,c6=0.f,c7=0.f;
        int j = 0;
        for (; j + 8 <= NA; j += 8) {
            c0 += bb[(j+0)*NA]; c1 += bb[(j+1)*NA];
            c2 += bb[(j+2)*NA]; c3 += bb[(j+3)*NA];
            c4 += bb[(j+4)*NA]; c5 += bb[(j+5)*NA];
            c6 += bb[(j+6)*NA]; c7 += bb[(j+7)*NA];
        }
        for (; j < NA; ++j) c0 += bb[j*NA];
        rs[t] = 1.f + (((c0+c1)+(c2+c3))+((c4+c5)+(c6+c7)));
    }
    __syncthreads();

    for (int d = 1; d <= ND; ++d) {
        if (t < KF * KF / 4)
            ((float4*)Wi)[t] = ((const float4*)(W_inner + d * KF * KF))[t];
        __syncthreads();

        float core[13];
#pragma unroll
        for (int it = 0; it < 13; ++it) {
            const int idx = t + it * 256;
            if (idx < NA * KF) {
                const int row = idx >> 5, f = idx & 31;
                float acc = b_inner[d * KF + f];
                const float* Sr = S + row * KF;
#pragma unroll
                for (int k = 0; k < KF; ++k) acc += Sr[k] * Wi[k * KF + f];
                core[it] = acc;
            }
        }
        __syncthreads();
#pragma unroll
        for (int it = 0; it < 13; ++it) {
            const int idx = t + it * 256;
            if (idx < NA * KF) {
                const int row = idx >> 5;
                const float cc  = core[it];
                const float old = attr[idx];
                attr[idx] = cc;
                S[idx] += rs[row] * (cc - old);
                attrAll[(size_t)b * (ND + 1) * NA * KF + (size_t)d * NA * KF + idx] = cc;
            }
        }
        __syncthreads();
    }
}

// ---------------------------------------------------------------------------
// Phase 2b: one block per (b,d): fpPart[d][b][u] = sum_i softmax(attr_i@Wout[d]+bout[d])[u]
// 8 waves x 8 rows per wave-pass (R=8): 100 rows = 13 wave-passes -> weight
// LDS traffic halves vs R=4. attr reads are wave-uniform broadcasts (free).
// attrL padded to 104 rows (zeroed) so unguarded MAC on rows 100..103 is safe;
// their softmax contribution is guarded out.
// ---------------------------------------------------------------------------
__global__ __launch_bounds__(512, 4) void p2b_fp(
    const float* __restrict__ attrAll, const float* __restrict__ W_output,
    const float* __restrict__ b_output, float* __restrict__ fpPart)
{
    extern __shared__ float sm[];
    float* Wl    = sm;            // [32*512] = 64 KB
    float* attrL = sm + KF * NU;  // [104*32] = 13.3 KB

    const int blk  = blockIdx.x;
    const int b    = blk & (NB - 1);
    const int d    = blk >> 7;
    const int t    = threadIdx.x;
    const int lane = t & 63;
    const int w    = t >> 6;

    const float4* wo4 = (const float4*)(W_output + (size_t)d * KF * NU);
    for (int idx = t; idx < KF * NU / 4; idx += 512) ((float4*)Wl)[idx] = wo4[idx];
    const float4* a4 = (const float4*)(attrAll + ((size_t)b * (ND + 1) + d) * NA * KF);
    for (int idx = t; idx < NA * KF / 4; idx += 512) ((float4*)attrL)[idx] = a4[idx];
    if (t < (104 - NA) * KF) attrL[NA * KF + t] = 0.f;    // zero pad rows 100..103

    const float4 bv0 = *(const float4*)&b_output[d * NU + lane * 4];
    const float4 bv1 = *(const float4*)&b_output[d * NU + 256 + lane * 4];

    float fpacc[8];
#pragma unroll
    for (int c = 0; c < 8; ++c) fpacc[c] = 0.f;

    __syncthreads();

#pragma unroll
    for (int p = 0; p < 2; ++p) {
        const int r0 = p * 64 + w * 8;
        if (r0 >= NA) continue;                      // wave-uniform
        float acc[8][8];
#pragma unroll
        for (int r = 0; r < 8; ++r) {
            acc[r][0] = bv0.x; acc[r][1] = bv0.y; acc[r][2] = bv0.z; acc[r][3] = bv0.w;
            acc[r][4] = bv1.x; acc[r][5] = bv1.y; acc[r][6] = bv1.z; acc[r][7] = bv1.w;
        }
        for (int k4 = 0; k4 < KF; k4 += 4) {
#pragma unroll
            for (int kk = 0; kk < 4; ++kk) {
                const float4 w0 = *(const float4*)&Wl[(k4 + kk) * NU + lane * 4];
                const float4 w1 = *(const float4*)&Wl[(k4 + kk) * NU + 256 + lane * 4];
#pragma unroll
                for (int r = 0; r < 8; ++r) {
                    const float a = attrL[(r0 + r) * KF + k4 + kk];   // broadcast
                    acc[r][0] += a * w0.x; acc[r][1] += a * w0.y;
                    acc[r][2] += a * w0.z; acc[r][3] += a * w0.w;
                    acc[r][4] += a * w1.x; acc[r][5] += a * w1.y;
                    acc[r][6] += a * w1.z; acc[r][7] += a * w1.w;
                }
            }
        }
#pragma unroll
        for (int r = 0; r < 8; ++r) {
            if (r0 + r >= NA) continue;
            float m = acc[r][0];
#pragma unroll
            for (int c = 1; c < 8; ++c) m = fmaxf(m, acc[r][c]);
#pragma unroll
            for (int off = 32; off > 0; off >>= 1) m = fmaxf(m, __shfl_xor(m, off, 64));
            float e[8], s = 0.f;
#pragma unroll
            for (int c = 0; c < 8; ++c) { e[c] = __expf(acc[r][c] - m); s += e[c]; }
#pragma unroll
            for (int off = 32; off > 0; off >>= 1) s += __shfl_xor(s, off, 64);
            const float inv = 1.f / s;
#pragma unroll
            for (int c = 0; c < 8; ++c) fpacc[c] += e[c] * inv;
        }
    }

    // cross-wave reduce (overlay on Wl)
    __syncthreads();
    float* fp8 = Wl;
    {
        float4 f0 = {fpacc[0], fpacc[1], fpacc[2], fpacc[3]};
        float4 f1 = {fpacc[4], fpacc[5], fpacc[6], fpacc[7]};
        *(float4*)&fp8[w * NU + lane * 4]       = f0;
        *(float4*)&fp8[w * NU + 256 + lane * 4] = f1;
    }
    __syncthreads();
    float s = fp8[t];
#pragma unroll
    for (int ww = 1; ww < 8; ++ww) s += fp8[ww * NU + t];
    fpPart[((size_t)d * NB + b) * NU + t] = s;
}

// ---------------------------------------------------------------------------
// Phase 2c: out[b][u] = sum_d fpPart[d][b][u]
// ---------------------------------------------------------------------------
__global__ __launch_bounds__(512) void p2c_out(const float* __restrict__ fpPart,
                                               float* __restrict__ out)
{
    const int b = blockIdx.x, t = threadIdx.x;
    float s = 0.f;
#pragma unroll
    for (int d = 0; d <= ND; ++d) s += fpPart[((size_t)d * NB + b) * NU + t];
    out[(size_t)b * NU + t] = s;
}

// ---------------------------------------------------------------------------
extern "C" void kernel_launch(void* const* d_in, const int* in_sizes, int n_in,
                              void* d_out, int out_size, void* d_ws, size_t ws_size,
                              hipStream_t stream) {
    (void)in_sizes; (void)n_in; (void)out_size; (void)ws_size;
    const float* x        = (const float*)d_in[0];
    const float* W_inner  = (const float*)d_in[1];
    const float* b_inner  = (const float*)d_in[2];
    const float* W_output = (const float*)d_in[3];
    const float* b_output = (const float*)d_in[4];
    float* out = (float*)d_out;

    float* S0      = (float*)d_ws;
    float* bonds   = S0 + SZ_S0;
    float* attrAll = bonds + SZ_BONDS;
    float* fpPart  = bonds;               // overlay: bonds dead after p2a

    p1_reduce<<<NB * NA, 256, 0, stream>>>(x, S0, attrAll, bonds);
    p2a_recur<<<NB, 256, 0, stream>>>(S0, bonds, W_inner, b_inner, attrAll);

    const size_t smemB = (size_t)(KF * NU + 104 * KF) * sizeof(float);  // 77.3 KB
    hipFuncSetAttribute(reinterpret_cast<const void*>(p2b_fp),
                        hipFuncAttributeMaxDynamicSharedMemorySize, (int)smemB);
    p2b_fp<<<NB * (ND + 1), 512, smemB, stream>>>(attrAll, W_output, b_output, fpPart);
    p2c_out<<<NB, 512, 0, stream>>>(fpPart, out);
}